// Round 4
// baseline (589.856 us; speedup 1.0000x reference)
//
#include <hip/hip_runtime.h>
#include <hip/hip_bf16.h>

// Problem constants
#define Bsz 128
#define Ssz 256
#define Lsz 200
#define Dsz 768
#define POS_DIM 50
#define TAGS 5
#define NROW 25600          // B*L
#define FIN 818             // D + POS_DIM
#define KH 832              // FIN padded to mult of 32
#define KD 160              // HID=150 padded

typedef __attribute__((ext_vector_type(8))) short short8;
typedef __attribute__((ext_vector_type(4))) short short4v;
typedef __attribute__((ext_vector_type(4))) float floatx4;

__device__ __forceinline__ short f2bf(float v) {
    __hip_bfloat16 h = __float2bfloat16(v);
    short s; __builtin_memcpy(&s, &h, 2); return s;
}
__device__ __forceinline__ float bf2f(short s) {
    __hip_bfloat16 h; __builtin_memcpy(&h, &s, 2);
    return __bfloat162float(h);
}

__device__ __forceinline__ void gload16(const short* g, short* l) {
    __builtin_amdgcn_global_load_lds(
        (const __attribute__((address_space(1))) void*)g,
        (__attribute__((address_space(3))) void*)l, 16, 0, 0);
}

// ---------------------------------------------------------------------------
// prep: Wbi_bf [640][160] bf16 (zero-padded), b2 = bh + Wh@br (the folded
// hidden bias, 640 fp32), bbi_pad[640] (= W_bi[:,150]).
// ---------------------------------------------------------------------------
__global__ void prep_kernel(const float* __restrict__ W_ap, const float* __restrict__ W_op,
                            const float* __restrict__ W_ap2, const float* __restrict__ W_op2,
                            const float* __restrict__ W_bi,
                            const float* __restrict__ b_reduc,
                            const float* __restrict__ b_ap, const float* __restrict__ b_op,
                            const float* __restrict__ b_ap2, const float* __restrict__ b_op2,
                            short* __restrict__ Wbi_bf,
                            float* __restrict__ b2, float* __restrict__ bbi_pad)
{
    int i = blockIdx.x * blockDim.x + threadIdx.x;
    if (i < 640 * KD) {
        int r = i / KD, c = i % KD;
        Wbi_bf[i] = (r < 600 && c < 150) ? f2bf(W_bi[r * 151 + c]) : (short)0;
    }
    if (i < 640) {
        float v = 0.0f;
        if (i < 600) {
            const float* bs = (i < 150) ? b_ap : (i < 300) ? b_op : (i < 450) ? b_ap2 : b_op2;
            v = bs[i % 150];
            const float* wsrc = (i < 150) ? W_ap : (i < 300) ? W_op : (i < 450) ? W_ap2 : W_op2;
            const float* wrow = wsrc + (i % 150) * 400;
            float d = 0.0f;
            for (int c = 0; c < 400; ++c) d += wrow[c] * b_reduc[c];
            v += d;
        }
        b2[i] = v;
        bbi_pad[i] = (i < 600) ? W_bi[i * 151 + 150] : 0.0f;
    }
}

// ---------------------------------------------------------------------------
// fold: W2[r][k] = sum_c Whcat[r][c] * Wr_perm[c][k], fp32 accumulate,
// single bf16 rounding. Whcat rows: [W_ap;W_op;W_ap2;W_op2] (600 rows, pad
// to 640 zeros). Wr_perm cols: k<768 -> W_reduc[c][POS_DIM+k];
// 768<=k<818 -> W_reduc[c][k-768]; else 0 (matches h_bf's permuted layout).
// grid 80 blocks x 8 rows each; thread owns cols {tid, tid+256, tid+512,
// tid+768(<832)}.
// ---------------------------------------------------------------------------
__global__ __launch_bounds__(256) void fold_kernel(
    const float* __restrict__ W_ap, const float* __restrict__ W_op,
    const float* __restrict__ W_ap2, const float* __restrict__ W_op2,
    const float* __restrict__ W_reduc,
    short* __restrict__ W2_bf)
{
    __shared__ float whs[8][400];
    int r0 = blockIdx.x * 8;
    for (int idx = threadIdx.x; idx < 8 * 400; idx += 256) {
        int rr = idx / 400, c = idx % 400;
        int r = r0 + rr;
        float v = 0.0f;
        if (r < 600) {
            const float* src = (r < 150) ? W_ap : (r < 300) ? W_op : (r < 450) ? W_ap2 : W_op2;
            v = src[(r % 150) * 400 + c];
        }
        whs[rr][c] = v;
    }
    __syncthreads();
#pragma unroll
    for (int j = 0; j < 4; ++j) {
        int k = threadIdx.x + j * 256;
        if (k >= KH) break;
        int sc = 0; bool valid = true;
        if (k < 768)      sc = POS_DIM + k;
        else if (k < 818) sc = k - 768;
        else              valid = false;
        float acc[8] = {0, 0, 0, 0, 0, 0, 0, 0};
        if (valid) {
            for (int c = 0; c < 400; ++c) {
                float v = W_reduc[c * FIN + sc];
#pragma unroll
                for (int rr = 0; rr < 8; ++rr) acc[rr] += whs[rr][c] * v;
            }
        }
#pragma unroll
        for (int rr = 0; rr < 8; ++rr)
            W2_bf[(long)(r0 + rr) * KH + k] = f2bf(acc[rr]);
    }
}

// ---------------------------------------------------------------------------
// pool (permuted layout): h_bf[row][0:768]=span-mean bert (float4 reads),
// [768:818]=embed[tag], [818:832]=0. One row per block, short4 writes.
// ---------------------------------------------------------------------------
__global__ __launch_bounds__(256) void pool_kernel(
    const float* __restrict__ bert,
    const int* __restrict__ positions,
    const int* __restrict__ postag,
    const float* __restrict__ embed,
    short* __restrict__ h_bf)
{
    int row = blockIdx.x;
    int b = row / Lsz;
    int st = positions[row * 2 + 0];
    int en = positions[row * 2 + 1];
    int tag = postag[row];
    int span = en - st + 1;
    float inv = 1.0f / (float)span;
    const float* base = bert + ((long)b * Ssz + st) * Dsz;
    short* hr = h_bf + (long)row * KH;

    int t = threadIdx.x;
    int c0 = t * 4;                    // 4 columns per thread; 256*4=1024 >= 832
    if (c0 >= KH) return;
    short4v o;
    if (c0 < 768) {
        float4 s = {0.f, 0.f, 0.f, 0.f};
        for (int i = 0; i < span; ++i) {
            float4 v = *(const float4*)(base + i * Dsz + c0);
            s.x += v.x; s.y += v.y; s.z += v.z; s.w += v.w;
        }
        o.x = f2bf(s.x * inv); o.y = f2bf(s.y * inv);
        o.z = f2bf(s.z * inv); o.w = f2bf(s.w * inv);
    } else {
        const float* e = embed + tag * POS_DIM;
#pragma unroll
        for (int j = 0; j < 4; ++j) {
            int c = c0 + j - 768;      // embed idx
            float v = (c < POS_DIM) ? e[c] : 0.0f;
            ((short*)&o)[j] = f2bf(v);
        }
    }
    *(short4v*)(hr + c0) = o;
}

// ---------------------------------------------------------------------------
// MFMA bf16 GEMM, double-buffered: C[m,n] = sum_k A[m,k]*Bt[n,k].
// Tile 128(M)x128(N), BK=32, 4 waves in 2x2 quadrants, 4x4 mfma each.
// XCD-aware block swizzle (bijective, m204) when gridDim.z==1: each XCD gets
// a contiguous y-range so A-row re-reads across x-blocks hit the same L2.
// K-loop: stage(t+1) issued before compute(t); one barrier per step.
// Staging via global_load_lds width 16: 2 A-chunks + 2 B-chunks per thread,
// no conditionals (K mult of 32; B rows padded; A overrun lands in finite ws
// data — those rows/cols are discarded by the epilogue guards).
// LDS per buffer: slot = k8*128 + row for A (0..4095) and B (4096..8191).
// Epilogue modes:
//  0: outB[m*ldc+n] = bf(acc+bias[n]), n<Nv
//  1: hidden: n<600 -> hid4[(n/150)*NROW+m][n%150] = bf(relu(acc+bias[n]));
//     n in [600,640) -> zero pad cols
//  2: affine: n<600 -> aff[((m/200)*800+(m%200)*4+n/150)*160+n%150]
//     = bf(acc+bias[n]); n in [600,640) -> zero pads
//  3: outF[bz*sCb + m*ldc+n] = acc  (m<M, n<Nv)
// ---------------------------------------------------------------------------
__global__ __launch_bounds__(256) void gemm_mfma(
    const short* __restrict__ A, long long sAb, int lda,
    const short* __restrict__ Bt, long long sBb, int ldb,
    const float* __restrict__ bias,
    short* __restrict__ outB, float* __restrict__ outF, long long sCb, int ldc,
    int M, int Nv, int K, int mode)
{
    __shared__ __align__(16) short AB[16384];   // 2 buffers x 8192 (32 KB)

    int bz = blockIdx.z;
    A += (long long)bz * sAb;
    Bt += (long long)bz * sBb;

    int bx = blockIdx.x, by = blockIdx.y;
    if (gridDim.z == 1) {
        // bijective XCD swizzle (m204): xcd = orig & 7 gets a contiguous chunk
        int nwg = gridDim.x * gridDim.y;
        int orig = by * gridDim.x + bx;
        int q = nwg >> 3, r = nwg & 7;
        int xcd = orig & 7, idx = orig >> 3;
        int swz = (xcd < r ? xcd * (q + 1) : r * (q + 1) + (xcd - r) * q) + idx;
        bx = swz % gridDim.x;
        by = swz / gridDim.x;
    }

    int row0 = by * 128;
    int col0 = bx * 128;
    int tid = threadIdx.x;
    int lane = tid & 63;
    int wv = tid >> 6;
    int lm = lane & 15, lk = lane >> 4;
    int wr = (wv >> 1) * 64;           // wave row-quadrant
    int wc = (wv & 1) * 64;            // wave col-quadrant

    // staging: A chunks {tid, tid+256}, B chunks {tid, tid+256} of 512 each.
    // chunk c: row = c&127, k8 = c>>7; LDS slot == c (slot = k8*128+row).
    int c0 = tid, c1 = tid + 256;
    const short* gA0 = A + (long)(row0 + (c0 & 127)) * lda + (c0 >> 7) * 8;
    const short* gA1 = A + (long)(row0 + (c1 & 127)) * lda + (c1 >> 7) * 8;
    const short* gB0 = Bt + (long)(col0 + (c0 & 127)) * ldb + (c0 >> 7) * 8;
    const short* gB1 = Bt + (long)(col0 + (c1 & 127)) * ldb + (c1 >> 7) * 8;

    floatx4 acc[4][4];
#pragma unroll
    for (int i = 0; i < 4; ++i)
#pragma unroll
        for (int j = 0; j < 4; ++j)
            acc[i][j] = (floatx4){0.f, 0.f, 0.f, 0.f};

    // stage one BK=32 tile into buffer `buf`
    auto stage = [&](int buf, int koff) {
        short* base = &AB[buf * 8192];
        gload16(gA0 + koff, base + c0 * 8);
        gload16(gA1 + koff, base + c1 * 8);
        gload16(gB0 + koff, base + 4096 + c0 * 8);
        gload16(gB1 + koff, base + 4096 + c1 * 8);
    };
    // consume one BK=32 tile from buffer `buf`
    auto compute = [&](int buf) {
        const short* fa = &AB[buf * 8192 + (lk * 128 + wr + lm) * 8];
        const short* fb = &AB[buf * 8192 + 4096 + (lk * 128 + wc + lm) * 8];
        short8 a[4], b[4];
#pragma unroll
        for (int mt = 0; mt < 4; ++mt) a[mt] = *(const short8*)(fa + mt * 128);
#pragma unroll
        for (int nt = 0; nt < 4; ++nt) b[nt] = *(const short8*)(fb + nt * 128);
#pragma unroll
        for (int mt = 0; mt < 4; ++mt)
#pragma unroll
            for (int nt = 0; nt < 4; ++nt)
                acc[mt][nt] = __builtin_amdgcn_mfma_f32_16x16x32_bf16(
                    a[mt], b[nt], acc[mt][nt], 0, 0, 0);
    };

    int nt = K >> 5;
    stage(0, 0);
    __syncthreads();                   // prologue drain (latency exposed once)
    int cur = 0;
    for (int t = 0; t + 1 < nt; ++t) {
        stage(cur ^ 1, (t + 1) << 5);  // issue next tile's loads first
        compute(cur);                  // ds_read + 16 MFMA hide the latency
        __syncthreads();               // vmcnt(0): next tile landed; lgkm done
        cur ^= 1;
    }
    compute(cur);                      // last tile, no barrier needed

    // epilogue
#pragma unroll
    for (int mt = 0; mt < 4; ++mt) {
#pragma unroll
        for (int nt = 0; nt < 4; ++nt) {
#pragma unroll
            for (int r = 0; r < 4; ++r) {
                int gm = row0 + wr + mt * 16 + lk * 4 + r;
                int gn = col0 + wc + nt * 16 + lm;
                float v = acc[mt][nt][r];
                if (mode == 0) {
                    if (gn < Nv)
                        outB[(long)gm * ldc + gn] = f2bf(v + bias[gn]);
                } else if (mode == 1) {
                    if (gn < 600) {
                        v = fmaxf(v + bias[gn], 0.0f);
                        outB[((long)(gn / 150) * NROW + gm) * KD + gn % 150] = f2bf(v);
                    } else if (gn < 640) {
                        int q = gn - 600;
                        outB[((long)(q / 10) * NROW + gm) * KD + 150 + q % 10] = 0;
                    }
                } else if (mode == 2) {
                    int bb = gm / 200, l = gm % 200;
                    if (gn < 600) {
                        v += bias[gn];
                        outB[((long)bb * 800 + l * 4 + gn / 150) * KD + gn % 150] = f2bf(v);
                    } else if (gn < 640) {
                        int q = gn - 600;
                        outB[((long)bb * 800 + l * 4 + q / 10) * KD + 150 + q % 10] = 0;
                    }
                } else {
                    if (gm < M && gn < Nv)
                        outF[(long long)bz * sCb + (long)gm * ldc + gn] = v;
                }
            }
        }
    }
}

// ---------------------------------------------------------------------------
// tags: per-row K=150 dots from bf16 ap_rep/op_rep (hid4[0], hid4[1])
// ---------------------------------------------------------------------------
__global__ __launch_bounds__(256) void tags_kernel(
    const short* __restrict__ hid4,
    const float* __restrict__ W_aptag, const float* __restrict__ b_aptag,
    const float* __restrict__ W_optag, const float* __restrict__ b_optag,
    float* __restrict__ out_ap, float* __restrict__ out_op)
{
    int wave = threadIdx.x / 64;
    int lane = threadIdx.x % 64;
    int row = blockIdx.x * 4 + wave;
    if (row >= NROW) return;

#pragma unroll
    for (int which = 0; which < 2; ++which) {
        const short* rep = hid4 + ((long)which * NROW + row) * KD;
        const float* W = which ? W_optag : W_aptag;
        const float* bb = which ? b_optag : b_aptag;
        float* out = which ? out_op : out_ap;
        float v0 = bf2f(rep[lane]);
        float v1 = bf2f(rep[64 + lane]);
        float v2 = (lane < 22) ? bf2f(rep[128 + lane]) : 0.0f;
#pragma unroll
        for (int t = 0; t < TAGS; ++t) {
            const float* w = W + t * 150;
            float p = v0 * w[lane] + v1 * w[64 + lane] +
                      ((lane < 22) ? v2 * w[128 + lane] : 0.0f);
#pragma unroll
            for (int off = 32; off > 0; off >>= 1) p += __shfl_down(p, off);
            if (lane == 0) out[row * TAGS + t] = p + bb[t];
        }
    }
}

// ---------------------------------------------------------------------------
extern "C" void kernel_launch(void* const* d_in, const int* in_sizes, int n_in,
                              void* d_out, int out_size, void* d_ws, size_t ws_size,
                              hipStream_t stream)
{
    const float* bert      = (const float*)d_in[0];
    const int*   positions = (const int*)d_in[1];
    const int*   postag    = (const int*)d_in[2];
    const float* embed     = (const float*)d_in[3];
    const float* W_reduc   = (const float*)d_in[4];
    const float* b_reduc   = (const float*)d_in[5];
    const float* W_ap      = (const float*)d_in[6];
    const float* b_ap      = (const float*)d_in[7];
    const float* W_op      = (const float*)d_in[8];
    const float* b_op      = (const float*)d_in[9];
    const float* W_ap2     = (const float*)d_in[10];
    const float* b_ap2     = (const float*)d_in[11];
    const float* W_op2     = (const float*)d_in[12];
    const float* b_op2     = (const float*)d_in[13];
    const float* W_aptag   = (const float*)d_in[14];
    const float* b_aptag   = (const float*)d_in[15];
    const float* W_optag   = (const float*)d_in[16];
    const float* b_optag   = (const float*)d_in[17];
    const float* W_bi      = (const float*)d_in[18];

    float* out = (float*)d_out;
    float* out_ap  = out;                       // [25600,5]
    float* out_op  = out + NROW * TAGS;         // [25600,5]
    float* out_tri = out + 2 * NROW * TAGS;     // [128,200,800]

    // workspace layout (shorts)
    short* ws = (short*)d_ws;
    short* h_bf     = ws;                               // 25600*832 = 21,299,200
    short* affine   = h_bf;                             // alias (h dead after hid GEMM)
    short* hid4     = h_bf + (long)NROW * KH;           // 4*25600*160
    short* W2_bf    = hid4 + (long)4 * NROW * KD;       // 640*832
    short* Wbi_bf   = W2_bf + 640 * KH;                 // 640*160
    float* b2       = (float*)(Wbi_bf + 640 * KD);      // 640 (folded hidden bias)
    float* bbi_pad  = b2 + 640;                         // 640

    // 1. bias/Wbi prep (incl. folded bias b2 = bh + Wh@br)
    prep_kernel<<<(640 * KD + 255) / 256, 256, 0, stream>>>(
        W_ap, W_op, W_ap2, W_op2, W_bi,
        b_reduc, b_ap, b_op, b_ap2, b_op2,
        Wbi_bf, b2, bbi_pad);

    // 2. fold W2 = Wh @ Wr (fp32 accumulate, bf16 out, permuted cols)
    fold_kernel<<<80, 256, 0, stream>>>(W_ap, W_op, W_ap2, W_op2, W_reduc, W2_bf);

    // 3. pool -> h_bf [25600][832] (bert-first permuted layout)
    pool_kernel<<<NROW, 256, 0, stream>>>(bert, positions, postag, embed, h_bf);

    // 4. hid4 = relu(h @ W2^T + b2)  M=25600 N=640 K=832; grid 5x200=1000
    {
        dim3 g(5, NROW / 128, 1);
        gemm_mfma<<<g, 256, 0, stream>>>(h_bf, 0, KH, W2_bf, 0, KH, b2,
                                         hid4, nullptr, 0, 0,
                                         NROW, 600, KH, 1);
    }
    // 5. tag heads
    tags_kernel<<<NROW / 4, 256, 0, stream>>>(hid4, W_aptag, b_aptag,
                                              W_optag, b_optag, out_ap, out_op);
    // 6. affine = ap_node @ Wbi^T + bbi -> scattered [128][800][160] bf16
    {
        dim3 g(5, NROW / 128, 1);
        gemm_mfma<<<g, 256, 0, stream>>>(hid4 + (long)2 * NROW * KD, 0, KD,
                                         Wbi_bf, 0, KD, bbi_pad,
                                         affine, nullptr, 0, 0,
                                         NROW, 600, KD, 2);
    }
    // 7. tri: per batch, C[l2][k] = op_node[l2,:]·affine[k,:]; grid 7x2x128
    {
        dim3 g(7, 2, Bsz);
        gemm_mfma<<<g, 256, 0, stream>>>(hid4 + (long)3 * NROW * KD, (long long)200 * KD, KD,
                                         affine, (long long)800 * KD, KD, nullptr,
                                         nullptr, out_tri, (long long)200 * 800, 800,
                                         200, 800, KD, 3);
    }
}

// Round 5
// 451.731 us; speedup vs baseline: 1.3058x; 1.3058x over previous
//
#include <hip/hip_runtime.h>
#include <hip/hip_bf16.h>

// Problem constants
#define Bsz 128
#define Ssz 256
#define Lsz 200
#define Dsz 768
#define POS_DIM 50
#define TAGS 5
#define NROW 25600          // B*L
#define FIN 818             // D + POS_DIM
#define KH 832              // FIN padded to mult of 32
#define KD 160              // HID=150 padded
#define KW 416              // fold inner dim (REDUC=400 padded)

typedef __attribute__((ext_vector_type(8))) short short8;
typedef __attribute__((ext_vector_type(4))) short short4v;
typedef __attribute__((ext_vector_type(4))) float floatx4;

__device__ __forceinline__ short f2bf(float v) {
    __hip_bfloat16 h = __float2bfloat16(v);
    short s; __builtin_memcpy(&s, &h, 2); return s;
}
__device__ __forceinline__ float bf2f(short s) {
    __hip_bfloat16 h; __builtin_memcpy(&h, &s, 2);
    return __bfloat162float(h);
}

__device__ __forceinline__ void gload16(const short* g, short* l) {
    __builtin_amdgcn_global_load_lds(
        (const __attribute__((address_space(1))) void*)g,
        (__attribute__((address_space(3))) void*)l, 16, 0, 0);
}

// ---------------------------------------------------------------------------
// prep:
//  Wh_bf  [640][416]  rows = [W_ap;W_op;W_ap2;W_op2] (600 used), zero-pad
//  WrT_bf [896][416]  WrT[k][c] = W_reduc[c][perm(k)]  (transposed+permuted:
//                     perm(k)=POS_DIM+k for k<768; k-768 for 768<=k<818; 0 pad)
//  Wbi_bf [640][160]  biaffine weight, zero-pad
//  b2[640] = bh + Wh@br (folded hidden bias), bbi_pad[640] (= W_bi[:,150])
// ---------------------------------------------------------------------------
__global__ void prep_kernel(const float* __restrict__ W_reduc,
                            const float* __restrict__ W_ap, const float* __restrict__ W_op,
                            const float* __restrict__ W_ap2, const float* __restrict__ W_op2,
                            const float* __restrict__ W_bi,
                            const float* __restrict__ b_reduc,
                            const float* __restrict__ b_ap, const float* __restrict__ b_op,
                            const float* __restrict__ b_ap2, const float* __restrict__ b_op2,
                            short* __restrict__ Wh_bf, short* __restrict__ WrT_bf,
                            short* __restrict__ Wbi_bf,
                            float* __restrict__ b2, float* __restrict__ bbi_pad)
{
    int i = blockIdx.x * blockDim.x + threadIdx.x;
    if (i < 640 * KW) {
        int r = i / KW, c = i % KW;
        float v = 0.0f;
        if (r < 600 && c < 400) {
            const float* src = (r < 150) ? W_ap : (r < 300) ? W_op : (r < 450) ? W_ap2 : W_op2;
            v = src[(r % 150) * 400 + c];
        }
        Wh_bf[i] = f2bf(v);
    }
    if (i < 896 * KW) {
        int k = i / KW, c = i % KW;
        float v = 0.0f;
        if (c < 400) {
            int sc = -1;
            if (k < 768)      sc = POS_DIM + k;
            else if (k < 818) sc = k - 768;
            if (sc >= 0) v = W_reduc[c * FIN + sc];
        }
        WrT_bf[i] = f2bf(v);
    }
    if (i < 640 * KD) {
        int r = i / KD, c = i % KD;
        Wbi_bf[i] = (r < 600 && c < 150) ? f2bf(W_bi[r * 151 + c]) : (short)0;
    }
    if (i < 640) {
        float v = 0.0f;
        if (i < 600) {
            const float* bs = (i < 150) ? b_ap : (i < 300) ? b_op : (i < 450) ? b_ap2 : b_op2;
            v = bs[i % 150];
            const float* wsrc = (i < 150) ? W_ap : (i < 300) ? W_op : (i < 450) ? W_ap2 : W_op2;
            const float* wrow = wsrc + (i % 150) * 400;
            float d = 0.0f;
            for (int c = 0; c < 400; ++c) d += wrow[c] * b_reduc[c];
            v += d;
        }
        b2[i] = v;
        bbi_pad[i] = (i < 600) ? W_bi[i * 151 + 150] : 0.0f;
    }
}

// ---------------------------------------------------------------------------
// pool (permuted layout): h_bf[row][0:768]=span-mean bert (float4 reads),
// [768:818]=embed[tag], [818:832]=0. One row per block, short4 writes.
// ---------------------------------------------------------------------------
__global__ __launch_bounds__(256) void pool_kernel(
    const float* __restrict__ bert,
    const int* __restrict__ positions,
    const int* __restrict__ postag,
    const float* __restrict__ embed,
    short* __restrict__ h_bf)
{
    int row = blockIdx.x;
    int b = row / Lsz;
    int st = positions[row * 2 + 0];
    int en = positions[row * 2 + 1];
    int tag = postag[row];
    int span = en - st + 1;
    float inv = 1.0f / (float)span;
    const float* base = bert + ((long)b * Ssz + st) * Dsz;
    short* hr = h_bf + (long)row * KH;

    int t = threadIdx.x;
    int c0 = t * 4;                    // 4 columns per thread; 256*4=1024 >= 832
    if (c0 >= KH) return;
    short4v o;
    if (c0 < 768) {
        float4 s = {0.f, 0.f, 0.f, 0.f};
        for (int i = 0; i < span; ++i) {
            float4 v = *(const float4*)(base + i * Dsz + c0);
            s.x += v.x; s.y += v.y; s.z += v.z; s.w += v.w;
        }
        o.x = f2bf(s.x * inv); o.y = f2bf(s.y * inv);
        o.z = f2bf(s.z * inv); o.w = f2bf(s.w * inv);
    } else {
        const float* e = embed + tag * POS_DIM;
#pragma unroll
        for (int j = 0; j < 4; ++j) {
            int c = c0 + j - 768;      // embed idx
            float v = (c < POS_DIM) ? e[c] : 0.0f;
            ((short*)&o)[j] = f2bf(v);
        }
    }
    *(short4v*)(hr + c0) = o;
}

// ---------------------------------------------------------------------------
// MFMA bf16 GEMM, double-buffered, BK=32: C[m,n] = sum_k A[m,k]*Bt[n,k].
// Tile 128(M)x128(N), 4 waves in 2x2 quadrants, 4x4 mfma each.
// XCD-aware bijective block swizzle (m204) when gridDim.z==1.
// K-loop: stage(t+1) issued before compute(t); one barrier per step.
// Staging via global_load_lds width 16: 2 A + 2 B chunks per thread; no
// conditionals (K mult of 32; overruns land in allocated ws, discarded by
// epilogue guards). LDS slot = k8*128+row, A 0..4095, B 4096..8191 shorts.
// Epilogue modes:
//  0: outB[m*ldc+n] = bf(acc+bias[n]), n<Nv
//  1: hidden: n<600 -> hid4[(n/150)*NROW+m][n%150] = bf(relu(acc+bias[n]));
//     n in [600,640) -> zero pad cols
//  2: affine: n<600 -> aff[((m/200)*800+(m%200)*4+n/150)*160+n%150]
//     = bf(acc+bias[n]); n in [600,640) -> zero pads
//  3: outF[bz*sCb + m*ldc+n] = acc  (m<M, n<Nv)
//  4: outB[m*ldc+n] = bf(acc), n<Nv (no bias; weight-fold GEMM)
// ---------------------------------------------------------------------------
__global__ __launch_bounds__(256) void gemm_mfma(
    const short* __restrict__ A, long long sAb, int lda,
    const short* __restrict__ Bt, long long sBb, int ldb,
    const float* __restrict__ bias,
    short* __restrict__ outB, float* __restrict__ outF, long long sCb, int ldc,
    int M, int Nv, int K, int mode)
{
    __shared__ __align__(16) short AB[16384];   // 2 buffers x 8192 (32 KB)

    int bz = blockIdx.z;
    A += (long long)bz * sAb;
    Bt += (long long)bz * sBb;

    int bx = blockIdx.x, by = blockIdx.y;
    if (gridDim.z == 1) {
        int nwg = gridDim.x * gridDim.y;
        int orig = by * gridDim.x + bx;
        int q = nwg >> 3, r = nwg & 7;
        int xcd = orig & 7, idx = orig >> 3;
        int swz = (xcd < r ? xcd * (q + 1) : r * (q + 1) + (xcd - r) * q) + idx;
        bx = swz % gridDim.x;
        by = swz / gridDim.x;
    }

    int row0 = by * 128;
    int col0 = bx * 128;
    int tid = threadIdx.x;
    int lane = tid & 63;
    int wv = tid >> 6;
    int lm = lane & 15, lk = lane >> 4;
    int wr = (wv >> 1) * 64;           // wave row-quadrant
    int wc = (wv & 1) * 64;            // wave col-quadrant

    int c0 = tid, c1 = tid + 256;
    const short* gA0 = A + (long)(row0 + (c0 & 127)) * lda + (c0 >> 7) * 8;
    const short* gA1 = A + (long)(row0 + (c1 & 127)) * lda + (c1 >> 7) * 8;
    const short* gB0 = Bt + (long)(col0 + (c0 & 127)) * ldb + (c0 >> 7) * 8;
    const short* gB1 = Bt + (long)(col0 + (c1 & 127)) * ldb + (c1 >> 7) * 8;

    floatx4 acc[4][4];
#pragma unroll
    for (int i = 0; i < 4; ++i)
#pragma unroll
        for (int j = 0; j < 4; ++j)
            acc[i][j] = (floatx4){0.f, 0.f, 0.f, 0.f};

    auto stage = [&](int buf, int koff) {
        short* base = &AB[buf * 8192];
        gload16(gA0 + koff, base + c0 * 8);
        gload16(gA1 + koff, base + c1 * 8);
        gload16(gB0 + koff, base + 4096 + c0 * 8);
        gload16(gB1 + koff, base + 4096 + c1 * 8);
    };
    auto compute = [&](int buf) {
        const short* fa = &AB[buf * 8192 + (lk * 128 + wr + lm) * 8];
        const short* fb = &AB[buf * 8192 + 4096 + (lk * 128 + wc + lm) * 8];
        short8 a[4], b[4];
#pragma unroll
        for (int mt = 0; mt < 4; ++mt) a[mt] = *(const short8*)(fa + mt * 128);
#pragma unroll
        for (int nt = 0; nt < 4; ++nt) b[nt] = *(const short8*)(fb + nt * 128);
#pragma unroll
        for (int mt = 0; mt < 4; ++mt)
#pragma unroll
            for (int nt = 0; nt < 4; ++nt)
                acc[mt][nt] = __builtin_amdgcn_mfma_f32_16x16x32_bf16(
                    a[mt], b[nt], acc[mt][nt], 0, 0, 0);
    };

    int nt = K >> 5;
    stage(0, 0);
    __syncthreads();
    int cur = 0;
    for (int t = 0; t + 1 < nt; ++t) {
        stage(cur ^ 1, (t + 1) << 5);
        compute(cur);
        __syncthreads();
        cur ^= 1;
    }
    compute(cur);

    // epilogue
#pragma unroll
    for (int mt = 0; mt < 4; ++mt) {
#pragma unroll
        for (int nt = 0; nt < 4; ++nt) {
#pragma unroll
            for (int r = 0; r < 4; ++r) {
                int gm = row0 + wr + mt * 16 + lk * 4 + r;
                int gn = col0 + wc + nt * 16 + lm;
                float v = acc[mt][nt][r];
                if (mode == 0 || mode == 4) {
                    if (gn < Nv)
                        outB[(long)gm * ldc + gn] = f2bf(mode == 0 ? v + bias[gn] : v);
                } else if (mode == 1) {
                    if (gn < 600) {
                        v = fmaxf(v + bias[gn], 0.0f);
                        outB[((long)(gn / 150) * NROW + gm) * KD + gn % 150] = f2bf(v);
                    } else if (gn < 640) {
                        int q = gn - 600;
                        outB[((long)(q / 10) * NROW + gm) * KD + 150 + q % 10] = 0;
                    }
                } else if (mode == 2) {
                    int bb = gm / 200, l = gm % 200;
                    if (gn < 600) {
                        v += bias[gn];
                        outB[((long)bb * 800 + l * 4 + gn / 150) * KD + gn % 150] = f2bf(v);
                    } else if (gn < 640) {
                        int q = gn - 600;
                        outB[((long)bb * 800 + l * 4 + q / 10) * KD + 150 + q % 10] = 0;
                    }
                } else {
                    if (gm < M && gn < Nv)
                        outF[(long long)bz * sCb + (long)gm * ldc + gn] = v;
                }
            }
        }
    }
}

// ---------------------------------------------------------------------------
// hid GEMM, BK=64 variant: tile 64(M)x128(N), double-buffered, 13 K-steps
// for K=832 (vs 26 at BK=32) — halves the per-step barrier/latency rounds.
// 4 waves: wave wv owns all 64 rows x cols [wv*32,+32) -> acc[4][2];
// per step: 2 kk-groups x 8 mfma = 16 mfma/wave. LDS per buf: A 64x64 (8KB)
// + B 128x64 (16KB) = 12288 shorts; dbuf 48KB -> 3 blocks/CU.
// Staging: A chunks {tid,tid+256} (row=c&63,k8=c>>6), B chunks {tid+i*256}
// i<4 (row=c&127,k8=c>>7). Epilogue = mode 1 (hidden scatter), baked in.
// ---------------------------------------------------------------------------
__global__ __launch_bounds__(256) void gemm_mfma64(
    const short* __restrict__ A, int lda,
    const short* __restrict__ Bt, int ldb,
    const float* __restrict__ bias,
    short* __restrict__ outB, int K)
{
    __shared__ __align__(16) short AB[24576];   // 2 x 12288 (48 KB)

    int bx = blockIdx.x, by = blockIdx.y;
    {   // bijective XCD swizzle
        int nwg = gridDim.x * gridDim.y;
        int orig = by * gridDim.x + bx;
        int q = nwg >> 3, r = nwg & 7;
        int xcd = orig & 7, idx = orig >> 3;
        int swz = (xcd < r ? xcd * (q + 1) : r * (q + 1) + (xcd - r) * q) + idx;
        bx = swz % gridDim.x;
        by = swz / gridDim.x;
    }

    int row0 = by * 64;
    int col0 = bx * 128;
    int tid = threadIdx.x;
    int lane = tid & 63;
    int wv = tid >> 6;
    int lm = lane & 15, lk = lane >> 4;

    // A chunks: 512 total (64 rows x 8 k8); B chunks: 1024 (128 rows x 8 k8)
    int a0 = tid, a1 = tid + 256;
    const short* gA0 = A + (long)(row0 + (a0 & 63)) * lda + (a0 >> 6) * 8;
    const short* gA1 = A + (long)(row0 + (a1 & 63)) * lda + (a1 >> 6) * 8;
    const short* gB[4];
    int bc[4];
#pragma unroll
    for (int i = 0; i < 4; ++i) {
        bc[i] = tid + i * 256;
        gB[i] = Bt + (long)(col0 + (bc[i] & 127)) * ldb + (bc[i] >> 7) * 8;
    }

    floatx4 acc[4][2];
#pragma unroll
    for (int i = 0; i < 4; ++i)
#pragma unroll
        for (int j = 0; j < 2; ++j)
            acc[i][j] = (floatx4){0.f, 0.f, 0.f, 0.f};

    auto stage = [&](int buf, int koff) {
        short* base = &AB[buf * 12288];
        gload16(gA0 + koff, base + a0 * 8);
        gload16(gA1 + koff, base + a1 * 8);
#pragma unroll
        for (int i = 0; i < 4; ++i)
            gload16(gB[i] + koff, base + 4096 + bc[i] * 8);
    };
    auto compute = [&](int buf) {
        const short* base = &AB[buf * 12288];
#pragma unroll
        for (int kk = 0; kk < 2; ++kk) {
            const short* fa = base + ((kk * 4 + lk) * 64 + lm) * 8;
            const short* fb = base + 4096 + ((kk * 4 + lk) * 128 + wv * 32 + lm) * 8;
            short8 a[4], b[2];
#pragma unroll
            for (int mt = 0; mt < 4; ++mt) a[mt] = *(const short8*)(fa + mt * 128);
#pragma unroll
            for (int nt = 0; nt < 2; ++nt) b[nt] = *(const short8*)(fb + nt * 128);
#pragma unroll
            for (int mt = 0; mt < 4; ++mt)
#pragma unroll
                for (int nt = 0; nt < 2; ++nt)
                    acc[mt][nt] = __builtin_amdgcn_mfma_f32_16x16x32_bf16(
                        a[mt], b[nt], acc[mt][nt], 0, 0, 0);
        }
    };

    int nt = K >> 6;                   // 13 for K=832
    stage(0, 0);
    __syncthreads();
    int cur = 0;
    for (int t = 0; t + 1 < nt; ++t) {
        stage(cur ^ 1, (t + 1) << 6);
        compute(cur);
        __syncthreads();
        cur ^= 1;
    }
    compute(cur);

    // epilogue: mode-1 hidden scatter
#pragma unroll
    for (int mt = 0; mt < 4; ++mt) {
#pragma unroll
        for (int nt = 0; nt < 2; ++nt) {
#pragma unroll
            for (int r = 0; r < 4; ++r) {
                int gm = row0 + mt * 16 + lk * 4 + r;
                int gn = col0 + wv * 32 + nt * 16 + lm;
                float v = acc[mt][nt][r];
                if (gn < 600) {
                    v = fmaxf(v + bias[gn], 0.0f);
                    outB[((long)(gn / 150) * NROW + gm) * KD + gn % 150] = f2bf(v);
                } else if (gn < 640) {
                    int q = gn - 600;
                    outB[((long)(q / 10) * NROW + gm) * KD + 150 + q % 10] = 0;
                }
            }
        }
    }
}

// ---------------------------------------------------------------------------
// tags: per-row K=150 dots from bf16 ap_rep/op_rep (hid4[0], hid4[1])
// ---------------------------------------------------------------------------
__global__ __launch_bounds__(256) void tags_kernel(
    const short* __restrict__ hid4,
    const float* __restrict__ W_aptag, const float* __restrict__ b_aptag,
    const float* __restrict__ W_optag, const float* __restrict__ b_optag,
    float* __restrict__ out_ap, float* __restrict__ out_op)
{
    int wave = threadIdx.x / 64;
    int lane = threadIdx.x % 64;
    int row = blockIdx.x * 4 + wave;
    if (row >= NROW) return;

#pragma unroll
    for (int which = 0; which < 2; ++which) {
        const short* rep = hid4 + ((long)which * NROW + row) * KD;
        const float* W = which ? W_optag : W_aptag;
        const float* bb = which ? b_optag : b_aptag;
        float* out = which ? out_op : out_ap;
        float v0 = bf2f(rep[lane]);
        float v1 = bf2f(rep[64 + lane]);
        float v2 = (lane < 22) ? bf2f(rep[128 + lane]) : 0.0f;
#pragma unroll
        for (int t = 0; t < TAGS; ++t) {
            const float* w = W + t * 150;
            float p = v0 * w[lane] + v1 * w[64 + lane] +
                      ((lane < 22) ? v2 * w[128 + lane] : 0.0f);
#pragma unroll
            for (int off = 32; off > 0; off >>= 1) p += __shfl_down(p, off);
            if (lane == 0) out[row * TAGS + t] = p + bb[t];
        }
    }
}

// ---------------------------------------------------------------------------
extern "C" void kernel_launch(void* const* d_in, const int* in_sizes, int n_in,
                              void* d_out, int out_size, void* d_ws, size_t ws_size,
                              hipStream_t stream)
{
    const float* bert      = (const float*)d_in[0];
    const int*   positions = (const int*)d_in[1];
    const int*   postag    = (const int*)d_in[2];
    const float* embed     = (const float*)d_in[3];
    const float* W_reduc   = (const float*)d_in[4];
    const float* b_reduc   = (const float*)d_in[5];
    const float* W_ap      = (const float*)d_in[6];
    const float* b_ap      = (const float*)d_in[7];
    const float* W_op      = (const float*)d_in[8];
    const float* b_op      = (const float*)d_in[9];
    const float* W_ap2     = (const float*)d_in[10];
    const float* b_ap2     = (const float*)d_in[11];
    const float* W_op2     = (const float*)d_in[12];
    const float* b_op2     = (const float*)d_in[13];
    const float* W_aptag   = (const float*)d_in[14];
    const float* b_aptag   = (const float*)d_in[15];
    const float* W_optag   = (const float*)d_in[16];
    const float* b_optag   = (const float*)d_in[17];
    const float* W_bi      = (const float*)d_in[18];

    float* out = (float*)d_out;
    float* out_ap  = out;                       // [25600,5]
    float* out_op  = out + NROW * TAGS;         // [25600,5]
    float* out_tri = out + 2 * NROW * TAGS;     // [128,200,800]

    // workspace layout (shorts)
    short* ws = (short*)d_ws;
    short* h_bf     = ws;                               // 25600*832 = 21,299,200
    short* affine   = h_bf;                             // alias (h dead after hid GEMM)
    short* hid4     = h_bf + (long)NROW * KH;           // 4*25600*160 = 16,384,000
    short* W2_bf    = hid4 + (long)4 * NROW * KD;       // 640*832
    short* Wh_bf    = W2_bf + 640 * KH;                 // 640*416
    short* WrT_bf   = Wh_bf + 640 * KW;                 // 896*416
    short* Wbi_bf   = WrT_bf + 896 * KW;                // 640*160
    float* b2       = (float*)(Wbi_bf + 640 * KD);      // 640 (folded hidden bias)
    float* bbi_pad  = b2 + 640;                         // 640

    // 1. weight prep (Wh, WrT transposed+permuted, Wbi, folded bias b2)
    prep_kernel<<<(896 * KW + 255) / 256, 256, 0, stream>>>(
        W_reduc, W_ap, W_op, W_ap2, W_op2, W_bi,
        b_reduc, b_ap, b_op, b_ap2, b_op2,
        Wh_bf, WrT_bf, Wbi_bf, b2, bbi_pad);

    // 2. fold GEMM: W2[r][k] = sum_c Wh[r][c]*WrT[k][c]; M=640 N=832 K=416
    {
        dim3 g(7, 5, 1);
        gemm_mfma<<<g, 256, 0, stream>>>(Wh_bf, 0, KW, WrT_bf, 0, KW, nullptr,
                                         W2_bf, nullptr, 0, KH,
                                         640, KH, KW, 4);
    }

    // 3. pool -> h_bf [25600][832] (bert-first permuted layout)
    pool_kernel<<<NROW, 256, 0, stream>>>(bert, positions, postag, embed, h_bf);

    // 4. hid4 = relu(h @ W2^T + b2)  M=25600 N=640 K=832; BK=64, grid 5x400
    {
        dim3 g(5, NROW / 64, 1);
        gemm_mfma64<<<g, 256, 0, stream>>>(h_bf, KH, W2_bf, KH, b2, hid4, KH);
    }
    // 5. tag heads
    tags_kernel<<<NROW / 4, 256, 0, stream>>>(hid4, W_aptag, b_aptag,
                                              W_optag, b_optag, out_ap, out_op);
    // 6. affine = ap_node @ Wbi^T + bbi -> scattered [128][800][160] bf16
    {
        dim3 g(5, NROW / 128, 1);
        gemm_mfma<<<g, 256, 0, stream>>>(hid4 + (long)2 * NROW * KD, 0, KD,
                                         Wbi_bf, 0, KD, bbi_pad,
                                         affine, nullptr, 0, 0,
                                         NROW, 600, KD, 2);
    }
    // 7. tri: per batch, C[l2][k] = op_node[l2,:]·affine[k,:]; grid 7x2x128
    {
        dim3 g(7, 2, Bsz);
        gemm_mfma<<<g, 256, 0, stream>>>(hid4 + (long)3 * NROW * KD, (long long)200 * KD, KD,
                                         affine, (long long)800 * KD, KD, nullptr,
                                         nullptr, out_tri, (long long)200 * 800, 800,
                                         200, 800, KD, 3);
    }
}

// Round 6
// 426.923 us; speedup vs baseline: 1.3816x; 1.0581x over previous
//
#include <hip/hip_runtime.h>
#include <hip/hip_bf16.h>

// Problem constants
#define Bsz 128
#define Ssz 256
#define Lsz 200
#define Dsz 768
#define POS_DIM 50
#define TAGS 5
#define NROW 25600          // B*L
#define FIN 818             // D + POS_DIM
#define KH 832              // FIN padded to mult of 32
#define KD 160              // HID=150 padded
#define KW 416              // fold inner dim (REDUC=400 padded)

typedef __attribute__((ext_vector_type(8))) short short8;
typedef __attribute__((ext_vector_type(4))) short short4v;
typedef __attribute__((ext_vector_type(4))) float floatx4;

__device__ __forceinline__ short f2bf(float v) {
    __hip_bfloat16 h = __float2bfloat16(v);
    short s; __builtin_memcpy(&s, &h, 2); return s;
}
__device__ __forceinline__ float bf2f(short s) {
    __hip_bfloat16 h; __builtin_memcpy(&h, &s, 2);
    return __bfloat162float(h);
}

__device__ __forceinline__ void gload16(const short* g, short* l) {
    __builtin_amdgcn_global_load_lds(
        (const __attribute__((address_space(1))) void*)g,
        (__attribute__((address_space(3))) void*)l, 16, 0, 0);
}

// ---------------------------------------------------------------------------
// prep:
//  Wh_bf  [640][416]  rows = [W_ap;W_op;W_ap2;W_op2] (600 used), zero-pad
//  WrT_bf [896][416]  WrT[k][c] = W_reduc[c][perm(k)]  (transposed+permuted:
//                     perm(k)=POS_DIM+k for k<768; k-768 for 768<=k<818; 0 pad)
//  Wbi_bf [640][160]  biaffine weight, zero-pad
//  b2[640] = bh + Wh@br (folded hidden bias), bbi_pad[640] (= W_bi[:,150])
// ---------------------------------------------------------------------------
__global__ void prep_kernel(const float* __restrict__ W_reduc,
                            const float* __restrict__ W_ap, const float* __restrict__ W_op,
                            const float* __restrict__ W_ap2, const float* __restrict__ W_op2,
                            const float* __restrict__ W_bi,
                            const float* __restrict__ b_reduc,
                            const float* __restrict__ b_ap, const float* __restrict__ b_op,
                            const float* __restrict__ b_ap2, const float* __restrict__ b_op2,
                            short* __restrict__ Wh_bf, short* __restrict__ WrT_bf,
                            short* __restrict__ Wbi_bf,
                            float* __restrict__ b2, float* __restrict__ bbi_pad)
{
    int i = blockIdx.x * blockDim.x + threadIdx.x;
    if (i < 640 * KW) {
        int r = i / KW, c = i % KW;
        float v = 0.0f;
        if (r < 600 && c < 400) {
            const float* src = (r < 150) ? W_ap : (r < 300) ? W_op : (r < 450) ? W_ap2 : W_op2;
            v = src[(r % 150) * 400 + c];
        }
        Wh_bf[i] = f2bf(v);
    }
    if (i < 896 * KW) {
        int k = i / KW, c = i % KW;
        float v = 0.0f;
        if (c < 400) {
            int sc = -1;
            if (k < 768)      sc = POS_DIM + k;
            else if (k < 818) sc = k - 768;
            if (sc >= 0) v = W_reduc[c * FIN + sc];
        }
        WrT_bf[i] = f2bf(v);
    }
    if (i < 640 * KD) {
        int r = i / KD, c = i % KD;
        Wbi_bf[i] = (r < 600 && c < 150) ? f2bf(W_bi[r * 151 + c]) : (short)0;
    }
    if (i < 640) {
        float v = 0.0f;
        if (i < 600) {
            const float* bs = (i < 150) ? b_ap : (i < 300) ? b_op : (i < 450) ? b_ap2 : b_op2;
            v = bs[i % 150];
            const float* wsrc = (i < 150) ? W_ap : (i < 300) ? W_op : (i < 450) ? W_ap2 : W_op2;
            const float* wrow = wsrc + (i % 150) * 400;
            float d = 0.0f;
            for (int c = 0; c < 400; ++c) d += wrow[c] * b_reduc[c];
            v += d;
        }
        b2[i] = v;
        bbi_pad[i] = (i < 600) ? W_bi[i * 151 + 150] : 0.0f;
    }
}

// ---------------------------------------------------------------------------
// pool (permuted layout): h_bf[row][0:768]=span-mean bert (float4 reads),
// [768:818]=embed[tag], [818:832]=0. One row per block, short4 writes.
// ---------------------------------------------------------------------------
__global__ __launch_bounds__(256) void pool_kernel(
    const float* __restrict__ bert,
    const int* __restrict__ positions,
    const int* __restrict__ postag,
    const float* __restrict__ embed,
    short* __restrict__ h_bf)
{
    int row = blockIdx.x;
    int b = row / Lsz;
    int st = positions[row * 2 + 0];
    int en = positions[row * 2 + 1];
    int tag = postag[row];
    int span = en - st + 1;
    float inv = 1.0f / (float)span;
    const float* base = bert + ((long)b * Ssz + st) * Dsz;
    short* hr = h_bf + (long)row * KH;

    int t = threadIdx.x;
    int c0 = t * 4;                    // 4 columns per thread; 256*4=1024 >= 832
    if (c0 >= KH) return;
    short4v o;
    if (c0 < 768) {
        float4 s = {0.f, 0.f, 0.f, 0.f};
        for (int i = 0; i < span; ++i) {
            float4 v = *(const float4*)(base + i * Dsz + c0);
            s.x += v.x; s.y += v.y; s.z += v.z; s.w += v.w;
        }
        o.x = f2bf(s.x * inv); o.y = f2bf(s.y * inv);
        o.z = f2bf(s.z * inv); o.w = f2bf(s.w * inv);
    } else {
        const float* e = embed + tag * POS_DIM;
#pragma unroll
        for (int j = 0; j < 4; ++j) {
            int c = c0 + j - 768;      // embed idx
            float v = (c < POS_DIM) ? e[c] : 0.0f;
            ((short*)&o)[j] = f2bf(v);
        }
    }
    *(short4v*)(hr + c0) = o;
}

// ---------------------------------------------------------------------------
// MFMA bf16 GEMM, double-buffered, BK=32: C[m,n] = sum_k A[m,k]*Bt[n,k].
// Tile 128(M)x128(N), 4 waves in 2x2 quadrants, 4x4 mfma each.
// XCD-aware bijective block swizzle (m204) when gridDim.z==1.
// K-loop: stage(t+1) issued before compute(t); one barrier per step.
// Epilogue modes:
//  0: outB[m*ldc+n] = bf(acc+bias[n]), n<Nv
//  2: affine: n<600 -> aff[((m/200)*800+(m%200)*4+n/150)*160+n%150]
//     = bf(acc+bias[n]); n in [600,640) -> zero pads
//  3: outF[bz*sCb + m*ldc+n] = acc  (m<M, n<Nv)
//  4: outB[m*ldc+n] = bf(acc), n<Nv (no bias; weight-fold GEMM)
// ---------------------------------------------------------------------------
__global__ __launch_bounds__(256) void gemm_mfma(
    const short* __restrict__ A, long long sAb, int lda,
    const short* __restrict__ Bt, long long sBb, int ldb,
    const float* __restrict__ bias,
    short* __restrict__ outB, float* __restrict__ outF, long long sCb, int ldc,
    int M, int Nv, int K, int mode)
{
    __shared__ __align__(16) short AB[16384];   // 2 buffers x 8192 (32 KB)

    int bz = blockIdx.z;
    A += (long long)bz * sAb;
    Bt += (long long)bz * sBb;

    int bx = blockIdx.x, by = blockIdx.y;
    if (gridDim.z == 1) {
        int nwg = gridDim.x * gridDim.y;
        int orig = by * gridDim.x + bx;
        int q = nwg >> 3, r = nwg & 7;
        int xcd = orig & 7, idx = orig >> 3;
        int swz = (xcd < r ? xcd * (q + 1) : r * (q + 1) + (xcd - r) * q) + idx;
        bx = swz % gridDim.x;
        by = swz / gridDim.x;
    }

    int row0 = by * 128;
    int col0 = bx * 128;
    int tid = threadIdx.x;
    int lane = tid & 63;
    int wv = tid >> 6;
    int lm = lane & 15, lk = lane >> 4;
    int wr = (wv >> 1) * 64;           // wave row-quadrant
    int wc = (wv & 1) * 64;            // wave col-quadrant

    int c0 = tid, c1 = tid + 256;
    const short* gA0 = A + (long)(row0 + (c0 & 127)) * lda + (c0 >> 7) * 8;
    const short* gA1 = A + (long)(row0 + (c1 & 127)) * lda + (c1 >> 7) * 8;
    const short* gB0 = Bt + (long)(col0 + (c0 & 127)) * ldb + (c0 >> 7) * 8;
    const short* gB1 = Bt + (long)(col0 + (c1 & 127)) * ldb + (c1 >> 7) * 8;

    floatx4 acc[4][4];
#pragma unroll
    for (int i = 0; i < 4; ++i)
#pragma unroll
        for (int j = 0; j < 4; ++j)
            acc[i][j] = (floatx4){0.f, 0.f, 0.f, 0.f};

    auto stage = [&](int buf, int koff) {
        short* base = &AB[buf * 8192];
        gload16(gA0 + koff, base + c0 * 8);
        gload16(gA1 + koff, base + c1 * 8);
        gload16(gB0 + koff, base + 4096 + c0 * 8);
        gload16(gB1 + koff, base + 4096 + c1 * 8);
    };
    auto compute = [&](int buf) {
        const short* fa = &AB[buf * 8192 + (lk * 128 + wr + lm) * 8];
        const short* fb = &AB[buf * 8192 + 4096 + (lk * 128 + wc + lm) * 8];
        short8 a[4], b[4];
#pragma unroll
        for (int mt = 0; mt < 4; ++mt) a[mt] = *(const short8*)(fa + mt * 128);
#pragma unroll
        for (int nt = 0; nt < 4; ++nt) b[nt] = *(const short8*)(fb + nt * 128);
#pragma unroll
        for (int mt = 0; mt < 4; ++mt)
#pragma unroll
            for (int nt = 0; nt < 4; ++nt)
                acc[mt][nt] = __builtin_amdgcn_mfma_f32_16x16x32_bf16(
                    a[mt], b[nt], acc[mt][nt], 0, 0, 0);
    };

    int nt = K >> 5;
    stage(0, 0);
    __syncthreads();
    int cur = 0;
    for (int t = 0; t + 1 < nt; ++t) {
        stage(cur ^ 1, (t + 1) << 5);
        compute(cur);
        __syncthreads();
        cur ^= 1;
    }
    compute(cur);

    // epilogue
#pragma unroll
    for (int mt = 0; mt < 4; ++mt) {
#pragma unroll
        for (int nt = 0; nt < 4; ++nt) {
#pragma unroll
            for (int r = 0; r < 4; ++r) {
                int gm = row0 + wr + mt * 16 + lk * 4 + r;
                int gn = col0 + wc + nt * 16 + lm;
                float v = acc[mt][nt][r];
                if (mode == 0 || mode == 4) {
                    if (gn < Nv)
                        outB[(long)gm * ldc + gn] = f2bf(mode == 0 ? v + bias[gn] : v);
                } else if (mode == 2) {
                    int bb = gm / 200, l = gm % 200;
                    if (gn < 600) {
                        v += bias[gn];
                        outB[((long)bb * 800 + l * 4 + gn / 150) * KD + gn % 150] = f2bf(v);
                    } else if (gn < 640) {
                        int q = gn - 600;
                        outB[((long)bb * 800 + l * 4 + q / 10) * KD + 150 + q % 10] = 0;
                    }
                } else {
                    if (gm < M && gn < Nv)
                        outF[(long long)bz * sCb + (long)gm * ldc + gn] = v;
                }
            }
        }
    }
}

// ---------------------------------------------------------------------------
// hid GEMM — phase-interleaved counted-vmcnt pipeline (T3+T4+T5 port).
// C[m,n] = sum_k h[m,k]*W2[n,k]; M=25600 N=640 K=832 fixed.
// Tile 256(M)x128(N), BK=64, 8 waves (4M x 2N), per-wave 64x64 out
// (acc[4][4]), 32 MFMA per K-step. 3-slot LDS ring (3 x 48KB = 144KB):
// slot = A[64k x 256row] (16384 sh) + B[64k x 128row] (8192 sh).
// Per thread per K-step: 4 A + 2 B global_load_lds (width 16).
// Schedule per step t (slot s=t%3): entry s_waitcnt vmcnt(6) — waits slot
// t's 6 loads, leaves slot t+1's 6 in flight (vmcnt(0) only at t=nt-1) —
// then ONE barrier; 4 phases: phase p does {ds_read b-frags for n=p+1 |
// 2 gloads for slot t+2 | setprio(1); 8 MFMA for n=p; setprio(0)}.
// a-frags (8 x b128) + b(n=0) read up front. Ring safety: slot (t+2)%3 was
// last read at step t-1; all waves crossed the entry barrier of t after
// finishing those MFMAs. Epilogue: hidden scatter
//   n<600: hid4[(n/150)*NROW+m][n%150] = bf(relu(acc+b2[n]));
//   n in [600,640): zero pad cols.
// ---------------------------------------------------------------------------
__global__ __launch_bounds__(512, 2) void gemm_hid(
    const short* __restrict__ A,    // h_bf [25600][832]
    const short* __restrict__ Bt,   // W2_bf [640][832]
    const float* __restrict__ bias, // b2 [640]
    short* __restrict__ outB)       // hid4
{
    __shared__ __align__(16) short AB[73728];   // 3 x 24576 shorts (144 KB)

    int bx = blockIdx.x, by = blockIdx.y;
    {   // bijective XCD swizzle (nwg = 500)
        int nwg = gridDim.x * gridDim.y;
        int orig = by * gridDim.x + bx;
        int q = nwg >> 3, r = nwg & 7;
        int xcd = orig & 7, idx = orig >> 3;
        int swz = (xcd < r ? xcd * (q + 1) : r * (q + 1) + (xcd - r) * q) + idx;
        bx = swz % gridDim.x;
        by = swz / gridDim.x;
    }
    int row0 = by * 256;
    int col0 = bx * 128;
    int tid = threadIdx.x;
    int lane = tid & 63;
    int wv = tid >> 6;                 // 0..7
    int wm = wv >> 1;                  // 0..3: 64-row group
    int wn = wv & 1;                   // 0..1: 64-col group
    int lm = lane & 15, lk = lane >> 4;

    // staging chunks: A c in [0,2048): row=c&255,k8=c>>8, lds short idx = c*8
    //                 B c in [0,1024): row=c&127,k8=c>>7, lds short idx = 16384+c*8
    int cA[4], cB[2];
    const short* gA[4]; const short* gB[2];
#pragma unroll
    for (int i = 0; i < 4; ++i) {
        cA[i] = tid + i * 512;
        gA[i] = A + (long)(row0 + (cA[i] & 255)) * KH + (cA[i] >> 8) * 8;
    }
#pragma unroll
    for (int j = 0; j < 2; ++j) {
        cB[j] = tid + j * 512;
        gB[j] = Bt + (long)(col0 + (cB[j] & 127)) * KH + (cB[j] >> 7) * 8;
    }

    floatx4 acc[4][4];
#pragma unroll
    for (int i = 0; i < 4; ++i)
#pragma unroll
        for (int j = 0; j < 4; ++j)
            acc[i][j] = (floatx4){0.f, 0.f, 0.f, 0.f};

    // prologue: stage slots 0 (k=0) and 1 (k=64) -> 12 loads in flight
#pragma unroll
    for (int i = 0; i < 4; ++i) gload16(gA[i], &AB[cA[i] * 8]);
#pragma unroll
    for (int j = 0; j < 2; ++j) gload16(gB[j], &AB[16384 + cB[j] * 8]);
#pragma unroll
    for (int i = 0; i < 4; ++i) gload16(gA[i] + 64, &AB[24576 + cA[i] * 8]);
#pragma unroll
    for (int j = 0; j < 2; ++j) gload16(gB[j] + 64, &AB[24576 + 16384 + cB[j] * 8]);

#define NT 13
#pragma unroll
    for (int t = 0; t < NT; ++t) {
        const int s = t % 3;
        if (t < NT - 1) { asm volatile("s_waitcnt vmcnt(6)" ::: "memory"); }
        else           { asm volatile("s_waitcnt vmcnt(0)" ::: "memory"); }
        __builtin_amdgcn_sched_barrier(0);
        __builtin_amdgcn_s_barrier();
        __builtin_amdgcn_sched_barrier(0);

        const short* ab = &AB[s * 24576] + ((lk * 256) + wm * 64 + lm) * 8;
        const short* bb = &AB[s * 24576 + 16384] + ((lk * 128) + wn * 64 + lm) * 8;
        const bool st = (t + 2) < NT;
        const int s2 = (t + 2) % 3;
        const int koff2 = (t + 2) * 64;
        short* sbA = &AB[s2 * 24576];
        short* sbB = &AB[s2 * 24576 + 16384];

        short8 a[4][2], b[2][2];
        // up-front: all a-frags + b(n=0)
#pragma unroll
        for (int m = 0; m < 4; ++m) {
            a[m][0] = *(const short8*)(ab + m * 128);
            a[m][1] = *(const short8*)(ab + 8192 + m * 128);
        }
        b[0][0] = *(const short8*)(bb);
        b[0][1] = *(const short8*)(bb + 4096);

        // phase 0: read b(n=1); gload A0,A1(t+2); MFMA n=0
        b[1][0] = *(const short8*)(bb + 128);
        b[1][1] = *(const short8*)(bb + 4096 + 128);
        if (st) { gload16(gA[0] + koff2, sbA + cA[0] * 8);
                  gload16(gA[1] + koff2, sbA + cA[1] * 8); }
        __builtin_amdgcn_s_setprio(1);
#pragma unroll
        for (int m = 0; m < 4; ++m) {
            acc[m][0] = __builtin_amdgcn_mfma_f32_16x16x32_bf16(a[m][0], b[0][0], acc[m][0], 0, 0, 0);
            acc[m][0] = __builtin_amdgcn_mfma_f32_16x16x32_bf16(a[m][1], b[0][1], acc[m][0], 0, 0, 0);
        }
        __builtin_amdgcn_s_setprio(0);

        // phase 1: read b(n=2); gload A2,A3; MFMA n=1
        b[0][0] = *(const short8*)(bb + 256);
        b[0][1] = *(const short8*)(bb + 4096 + 256);
        if (st) { gload16(gA[2] + koff2, sbA + cA[2] * 8);
                  gload16(gA[3] + koff2, sbA + cA[3] * 8); }
        __builtin_amdgcn_s_setprio(1);
#pragma unroll
        for (int m = 0; m < 4; ++m) {
            acc[m][1] = __builtin_amdgcn_mfma_f32_16x16x32_bf16(a[m][0], b[1][0], acc[m][1], 0, 0, 0);
            acc[m][1] = __builtin_amdgcn_mfma_f32_16x16x32_bf16(a[m][1], b[1][1], acc[m][1], 0, 0, 0);
        }
        __builtin_amdgcn_s_setprio(0);

        // phase 2: read b(n=3); gload B0,B1; MFMA n=2
        b[1][0] = *(const short8*)(bb + 384);
        b[1][1] = *(const short8*)(bb + 4096 + 384);
        if (st) { gload16(gB[0] + koff2, sbB + cB[0] * 8);
                  gload16(gB[1] + koff2, sbB + cB[1] * 8); }
        __builtin_amdgcn_s_setprio(1);
#pragma unroll
        for (int m = 0; m < 4; ++m) {
            acc[m][2] = __builtin_amdgcn_mfma_f32_16x16x32_bf16(a[m][0], b[0][0], acc[m][2], 0, 0, 0);
            acc[m][2] = __builtin_amdgcn_mfma_f32_16x16x32_bf16(a[m][1], b[0][1], acc[m][2], 0, 0, 0);
        }
        __builtin_amdgcn_s_setprio(0);

        // phase 3: MFMA n=3
        __builtin_amdgcn_s_setprio(1);
#pragma unroll
        for (int m = 0; m < 4; ++m) {
            acc[m][3] = __builtin_amdgcn_mfma_f32_16x16x32_bf16(a[m][0], b[1][0], acc[m][3], 0, 0, 0);
            acc[m][3] = __builtin_amdgcn_mfma_f32_16x16x32_bf16(a[m][1], b[1][1], acc[m][3], 0, 0, 0);
        }
        __builtin_amdgcn_s_setprio(0);
    }
#undef NT

    // epilogue: hidden scatter (relu + bias), pad cols zeroed
#pragma unroll
    for (int m = 0; m < 4; ++m) {
#pragma unroll
        for (int n = 0; n < 4; ++n) {
#pragma unroll
            for (int r = 0; r < 4; ++r) {
                int gm = row0 + wm * 64 + m * 16 + lk * 4 + r;
                int gn = col0 + wn * 64 + n * 16 + lm;
                float v = acc[m][n][r];
                if (gn < 600) {
                    v = fmaxf(v + bias[gn], 0.0f);
                    outB[((long)(gn / 150) * NROW + gm) * KD + gn % 150] = f2bf(v);
                } else if (gn < 640) {
                    int q = gn - 600;
                    outB[((long)(q / 10) * NROW + gm) * KD + 150 + q % 10] = 0;
                }
            }
        }
    }
}

// ---------------------------------------------------------------------------
// tags: per-row K=150 dots from bf16 ap_rep/op_rep (hid4[0], hid4[1])
// ---------------------------------------------------------------------------
__global__ __launch_bounds__(256) void tags_kernel(
    const short* __restrict__ hid4,
    const float* __restrict__ W_aptag, const float* __restrict__ b_aptag,
    const float* __restrict__ W_optag, const float* __restrict__ b_optag,
    float* __restrict__ out_ap, float* __restrict__ out_op)
{
    int wave = threadIdx.x / 64;
    int lane = threadIdx.x % 64;
    int row = blockIdx.x * 4 + wave;
    if (row >= NROW) return;

#pragma unroll
    for (int which = 0; which < 2; ++which) {
        const short* rep = hid4 + ((long)which * NROW + row) * KD;
        const float* W = which ? W_optag : W_aptag;
        const float* bb = which ? b_optag : b_aptag;
        float* out = which ? out_op : out_ap;
        float v0 = bf2f(rep[lane]);
        float v1 = bf2f(rep[64 + lane]);
        float v2 = (lane < 22) ? bf2f(rep[128 + lane]) : 0.0f;
#pragma unroll
        for (int t = 0; t < TAGS; ++t) {
            const float* w = W + t * 150;
            float p = v0 * w[lane] + v1 * w[64 + lane] +
                      ((lane < 22) ? v2 * w[128 + lane] : 0.0f);
#pragma unroll
            for (int off = 32; off > 0; off >>= 1) p += __shfl_down(p, off);
            if (lane == 0) out[row * TAGS + t] = p + bb[t];
        }
    }
}

// ---------------------------------------------------------------------------
extern "C" void kernel_launch(void* const* d_in, const int* in_sizes, int n_in,
                              void* d_out, int out_size, void* d_ws, size_t ws_size,
                              hipStream_t stream)
{
    const float* bert      = (const float*)d_in[0];
    const int*   positions = (const int*)d_in[1];
    const int*   postag    = (const int*)d_in[2];
    const float* embed     = (const float*)d_in[3];
    const float* W_reduc   = (const float*)d_in[4];
    const float* b_reduc   = (const float*)d_in[5];
    const float* W_ap      = (const float*)d_in[6];
    const float* b_ap      = (const float*)d_in[7];
    const float* W_op      = (const float*)d_in[8];
    const float* b_op      = (const float*)d_in[9];
    const float* W_ap2     = (const float*)d_in[10];
    const float* b_ap2     = (const float*)d_in[11];
    const float* W_op2     = (const float*)d_in[12];
    const float* b_op2     = (const float*)d_in[13];
    const float* W_aptag   = (const float*)d_in[14];
    const float* b_aptag   = (const float*)d_in[15];
    const float* W_optag   = (const float*)d_in[16];
    const float* b_optag   = (const float*)d_in[17];
    const float* W_bi      = (const float*)d_in[18];

    float* out = (float*)d_out;
    float* out_ap  = out;                       // [25600,5]
    float* out_op  = out + NROW * TAGS;         // [25600,5]
    float* out_tri = out + 2 * NROW * TAGS;     // [128,200,800]

    // workspace layout (shorts)
    short* ws = (short*)d_ws;
    short* h_bf     = ws;                               // 25600*832 = 21,299,200
    short* affine   = h_bf;                             // alias (h dead after hid GEMM)
    short* hid4     = h_bf + (long)NROW * KH;           // 4*25600*160 = 16,384,000
    short* W2_bf    = hid4 + (long)4 * NROW * KD;       // 640*832
    short* Wh_bf    = W2_bf + 640 * KH;                 // 640*416
    short* WrT_bf   = Wh_bf + 640 * KW;                 // 896*416
    short* Wbi_bf   = WrT_bf + 896 * KW;                // 640*160
    float* b2       = (float*)(Wbi_bf + 640 * KD);      // 640 (folded hidden bias)
    float* bbi_pad  = b2 + 640;                         // 640

    // 1. weight prep (Wh, WrT transposed+permuted, Wbi, folded bias b2)
    prep_kernel<<<(896 * KW + 255) / 256, 256, 0, stream>>>(
        W_reduc, W_ap, W_op, W_ap2, W_op2, W_bi,
        b_reduc, b_ap, b_op, b_ap2, b_op2,
        Wh_bf, WrT_bf, Wbi_bf, b2, bbi_pad);

    // 2. fold GEMM: W2[r][k] = sum_c Wh[r][c]*WrT[k][c]; M=640 N=832 K=416
    {
        dim3 g(7, 5, 1);
        gemm_mfma<<<g, 256, 0, stream>>>(Wh_bf, 0, KW, WrT_bf, 0, KW, nullptr,
                                         W2_bf, nullptr, 0, KH,
                                         640, KH, KW, 4);
    }

    // 3. pool -> h_bf [25600][832] (bert-first permuted layout)
    pool_kernel<<<NROW, 256, 0, stream>>>(bert, positions, postag, embed, h_bf);

    // 4. hid4 = relu(h @ W2^T + b2)  M=25600 N=640 K=832; 256x128 tile,
    //    8-wave phase-interleaved counted-vmcnt pipeline; grid 5x100=500
    {
        dim3 g(5, NROW / 256, 1);
        gemm_hid<<<g, 512, 0, stream>>>(h_bf, W2_bf, b2, hid4);
    }
    // 5. tag heads
    tags_kernel<<<NROW / 4, 256, 0, stream>>>(hid4, W_aptag, b_aptag,
                                              W_optag, b_optag, out_ap, out_op);
    // 6. affine = ap_node @ Wbi^T + bbi -> scattered [128][800][160] bf16
    {
        dim3 g(5, NROW / 128, 1);
        gemm_mfma<<<g, 256, 0, stream>>>(hid4 + (long)2 * NROW * KD, 0, KD,
                                         Wbi_bf, 0, KD, bbi_pad,
                                         affine, nullptr, 0, 0,
                                         NROW, 600, KD, 2);
    }
    // 7. tri: per batch, C[l2][k] = op_node[l2,:]·affine[k,:]; grid 7x2x128
    {
        dim3 g(7, 2, Bsz);
        gemm_mfma<<<g, 256, 0, stream>>>(hid4 + (long)3 * NROW * KD, (long long)200 * KD, KD,
                                         affine, (long long)800 * KD, KD, nullptr,
                                         nullptr, out_tri, (long long)200 * 800, 800,
                                         200, 800, KD, 3);
    }
}